// Round 14
// baseline (3093.069 us; speedup 1.0000x reference)
//
#include <hip/hip_runtime.h>
#include <cstdint>
#include <cstddef>

typedef __attribute__((ext_vector_type(8))) short short8;
typedef __attribute__((ext_vector_type(4))) short short4v;
typedef __attribute__((ext_vector_type(4))) float f32x4;
typedef __attribute__((ext_vector_type(4))) int i32x4;

#define DEV __device__ __forceinline__

// Problem geometry (fixed by the reference)
constexpr int DD = 2048;           // D
constexpr int HHID = 8192;         // H
constexpr int BB = 4;              // B
constexpr int SS = 2048;           // S
constexpr size_t NX = (size_t)BB * SS * DD;   // 16,777,216
constexpr size_t NW = (size_t)DD * HHID;      // 16,777,216
constexpr size_t NH = (size_t)BB * SS * HHID; // 67,108,864

// Scratch layout (bytes)
constexpr size_t OFF_XH  = 0;                    // x bf16 hi (V path)
constexpr size_t OFF_XA1 = OFF_XH + NX * 2;      // x i8 lvl1
constexpr size_t OFF_XA2 = OFF_XA1 + NX;         // x i8 lvl2
constexpr size_t OFF_WA1 = OFF_XA2 + NX;         // weight i8 lvl1 (reused)
constexpr size_t OFF_WA2 = OFF_WA1 + NW;         // weight i8 lvl2
constexpr size_t OFF_WHV = OFF_WA1;              // alias: V-path bf16 weights (NW*2)
constexpr size_t OFF_HH  = OFF_WA2 + NW;         // h bf16 (V path) / ST alias
constexpr size_t OFF_PT  = OFF_HH + NH * 2;      // probs^T bf16
constexpr size_t OFF_HA1 = OFF_PT + NX * 2;      // h i8 (reused Q/K)
constexpr size_t OFF_HA2 = OFF_HA1 + NH;
constexpr size_t OFF_QA1 = OFF_HA2 + NH;         // Q i8
constexpr size_t OFF_QA2 = OFF_QA1 + NX;
constexpr size_t OFF_KA1 = OFF_QA2 + NX;         // K i8
constexpr size_t OFF_KA2 = OFF_KA1 + NX;
constexpr size_t OFF_V   = OFF_KA2 + NX;         // V bf16
constexpr size_t OFF_XS  = OFF_V + NX * 2;       // f32[8192] x row scales
constexpr size_t OFF_HS  = OFF_XS + 32768;       // f32[8192] h row scales
constexpr size_t OFF_QS  = OFF_HS + 32768;       // f32[8192] Q row scales
constexpr size_t OFF_KS  = OFF_QS + 32768;       // f32[8192] K row scales
constexpr size_t OFF_CM  = OFF_KS + 32768;       // colmax scratch
constexpr size_t OFF_TSH = OFF_CM + 32768;       // tile scales h: [8192][32] f32
constexpr size_t OFF_TSQ = OFF_TSH + 8192 * 32 * 4;  // tile scales Q/K: [8192][8] f32
constexpr size_t WS_TOTAL = OFF_TSQ + 8192 * 8 * 4;
constexpr size_t OFF_ST = OFF_HH;                // fp32 scores^T (67MB <= 134MB)

__device__ __align__(256) unsigned char g_ws[WS_TOTAL];

DEV unsigned char* wsbase(unsigned char* p) { return p ? p : (unsigned char*)g_ws; }
DEV short f2bf(float v) { __bf16 b = (__bf16)v; return __builtin_bit_cast(short, b); }
DEV float bf2f(short s) { return (float)__builtin_bit_cast(__bf16, s); }

template <typename T> DEV void nts(T v, T* p) { __builtin_nontemporal_store(v, p); }
template <typename T> DEV T ntl(const T* p) { return __builtin_nontemporal_load(p); }

DEV void gl16(const short* g, short* l) {
  __builtin_amdgcn_global_load_lds((const __attribute__((address_space(1))) void*)g,
                                   (__attribute__((address_space(3))) void*)l, 16, 0, 0);
}
DEV void gl16b(const signed char* g, signed char* l) {
  __builtin_amdgcn_global_load_lds((const __attribute__((address_space(1))) void*)g,
                                   (__attribute__((address_space(3))) void*)l, 16, 0, 0);
}

// grouped-row raster: concurrently-resident blocks form a 2D window in L2
DEV void raster2d(int rem, int gx, int grp, int& by, int& bx) {
  const int tpg = grp * gx;
  const int gidx = rem / tpg;
  const int o = rem - gidx * tpg;
  const int r = o / grp;
  by = gidx * grp + (o - r * grp);
  bx = r;
}

// ---------------------------------------------------------------------------
// cast x -> bf16 hi (V path)
// ---------------------------------------------------------------------------
__global__ void cast_hi_k(const float* __restrict__ x, unsigned char* wsb,
                          size_t oh, size_t n4) {
  unsigned char* ws = wsbase(wsb);
  short4v* OH = (short4v*)(ws + oh);
  const f32x4* X = (const f32x4*)x;
  for (size_t i = (size_t)blockIdx.x * blockDim.x + threadIdx.x; i < n4;
       i += (size_t)gridDim.x * blockDim.x) {
    const f32x4 v = ntl(&X[i]);
    short4v hs;
#pragma unroll
    for (int e = 0; e < 4; ++e) hs[e] = f2bf(v[e]);
    OH[i] = hs;
  }
}

// ---------------------------------------------------------------------------
// per-row 2-level i8 quantization of fp32 x (rowlen 2048)
// ---------------------------------------------------------------------------
__launch_bounds__(256)
__global__ void quant_x_k(const float* __restrict__ x, unsigned char* wsb,
                          size_t oa1, size_t oa2, size_t oxs) {
  unsigned char* ws = wsbase(wsb);
  signed char* A1 = (signed char*)(ws + oa1);
  signed char* A2 = (signed char*)(ws + oa2);
  float* XS = (float*)(ws + oxs);
  const int row = blockIdx.x;
  const float* xr = x + (size_t)row * 2048;
  const int tid = threadIdx.x, lane = tid & 63;
  const f32x4 v0 = *(const f32x4*)&xr[tid * 8];
  const f32x4 v1 = *(const f32x4*)&xr[tid * 8 + 4];
  float m = 0.0f;
#pragma unroll
  for (int e = 0; e < 4; ++e) m = fmaxf(m, fmaxf(fabsf(v0[e]), fabsf(v1[e])));
#pragma unroll
  for (int o = 32; o; o >>= 1) m = fmaxf(m, __shfl_xor(m, o));
  __shared__ float rb[4];
  if (lane == 0) rb[tid >> 6] = m;
  __syncthreads();
  m = fmaxf(fmaxf(rb[0], rb[1]), fmaxf(rb[2], rb[3]));
  const float inv = (m > 1e-30f) ? 127.0f / m : 0.0f;
  if (tid == 0) XS[row] = m * (1.0f / 127.0f);
  unsigned int w1a = 0, w1b = 0, w2a = 0, w2b = 0;
#pragma unroll
  for (int e = 0; e < 8; ++e) {
    const float xv = (e < 4) ? v0[e] : v1[e - 4];
    const float q = xv * inv;
    const float a1f = rintf(q);
    int ia2 = (int)rintf((q - a1f) * 256.0f);
    ia2 = ia2 > 127 ? 127 : (ia2 < -127 ? -127 : ia2);
    const unsigned int b1 = (unsigned char)(signed char)(int)a1f;
    const unsigned int b2 = (unsigned char)(signed char)ia2;
    if (e < 4) { w1a |= b1 << (8 * e); w2a |= b2 << (8 * e); }
    else       { w1b |= b1 << (8 * (e - 4)); w2b |= b2 << (8 * (e - 4)); }
  }
  const size_t o = (size_t)row * 2048 + tid * 8;
  *(unsigned int*)&A1[o] = w1a; *(unsigned int*)&A1[o + 4] = w1b;
  *(unsigned int*)&A2[o] = w2a; *(unsigned int*)&A2[o + 4] = w2b;
}

// ---------------------------------------------------------------------------
// rescale 2-level i8 rows from per-tile scales to the per-row max scale.
// ---------------------------------------------------------------------------
__launch_bounds__(256)
__global__ void rescale_k(unsigned char* wsb, size_t a1o, size_t a2o,
                          size_t tso, size_t so, int rowlen) {
  unsigned char* ws = wsbase(wsb);
  const int row = blockIdx.x, tid = threadIdx.x;
  const int nblk = rowlen >> 8;
  const float* TS = (const float*)(ws + tso) + (size_t)row * nblk;
  __shared__ float ratio[32];
  __shared__ float srow_sh;
  if (tid == 0) {
    float m = 0.0f;
    for (int i = 0; i < nblk; ++i) m = fmaxf(m, TS[i]);
    srow_sh = m;
    ((float*)(ws + so))[row] = m;
  }
  __syncthreads();
  const float srow = srow_sh;
  if (tid < nblk) ratio[tid] = (srow > 0.0f) ? TS[tid] / srow : 0.0f;
  __syncthreads();
  unsigned int* A1 = (unsigned int*)((signed char*)(ws + a1o) + (size_t)row * rowlen);
  unsigned int* A2 = (unsigned int*)((signed char*)(ws + a2o) + (size_t)row * rowlen);
  const int nu = rowlen >> 2;
  for (int u = tid; u < nu; u += 256) {
    const float r = ratio[u >> 6];
    if (r == 1.0f) continue;
    const unsigned int w1 = A1[u], w2 = A2[u];
    unsigned int o1 = 0, o2 = 0;
#pragma unroll
    for (int e = 0; e < 4; ++e) {
      const float a1 = (float)(signed char)(w1 >> (8 * e));
      const float a2 = (float)(signed char)(w2 >> (8 * e));
      const float f = r * (a1 + a2 * (1.0f / 256.0f));
      const float n1 = rintf(f);
      int i2 = (int)rintf((f - n1) * 256.0f);
      i2 = i2 > 127 ? 127 : (i2 < -127 ? -127 : i2);
      o1 |= ((unsigned int)(unsigned char)(signed char)(int)n1) << (8 * e);
      o2 |= ((unsigned int)(unsigned char)(signed char)i2) << (8 * e);
    }
    A1[u] = o1; A2[u] = o2;
  }
}

// ---------------------------------------------------------------------------
// per-column absmax of w [R][C] -> MX[col]
// ---------------------------------------------------------------------------
__launch_bounds__(256)
__global__ void colmax_k(const float* __restrict__ w, unsigned char* wsb,
                         size_t omax, int R, int C) {
  unsigned char* ws = wsbase(wsb);
  unsigned int* MX = (unsigned int*)(ws + omax);
  const int col = blockIdx.x * 256 + threadIdx.x;
  const int r0 = blockIdx.y * 128;
  float m = 0.0f;
  for (int r = 0; r < 128; ++r) m = fmaxf(m, fabsf(w[(size_t)(r0 + r) * C + col]));
  atomicMax(&MX[col], __float_as_uint(m));
}

// in-place: uint-encoded absmax -> f32 scale (max/127)
__global__ void scalefix_k(unsigned char* wsb, size_t off, int n) {
  unsigned char* ws = wsbase(wsb);
  const int i = blockIdx.x * 256 + threadIdx.x;
  if (i < n) {
    float* p = (float*)(ws + off);
    const unsigned int u = ((const unsigned int*)p)[i];
    p[i] = __uint_as_float(u) * (1.0f / 127.0f);
  }
}

// ---------------------------------------------------------------------------
// transpose + 2-level i8 quant: src R x C fp32 -> a1,a2 [C][R] i8
// ---------------------------------------------------------------------------
__global__ void transpose_quant_k(const float* __restrict__ src, unsigned char* wsb,
                                  size_t oa1, size_t oa2, size_t osc, int R, int C) {
  __shared__ float t[32][33];
  unsigned char* ws = wsbase(wsb);
  signed char* A1 = (signed char*)(ws + oa1);
  signed char* A2 = (signed char*)(ws + oa2);
  const float* SC = (const float*)(ws + osc);
  const int c0 = blockIdx.x << 5, r0 = blockIdx.y << 5;
  const int x = threadIdx.x, y = threadIdx.y;
#pragma unroll
  for (int i = 0; i < 4; ++i) {
    const int rr = y + (i << 3);
    t[rr][x] = ntl(&src[(size_t)(r0 + rr) * C + c0 + x]);
  }
  __syncthreads();
#pragma unroll
  for (int i = 0; i < 4; ++i) {
    const int oc = y + (i << 3);
    const float v = t[x][oc];
    const float s = SC[c0 + oc];
    const float inv = (s > 1e-38f) ? 1.0f / s : 0.0f;
    const float q = v * inv;
    const float a1f = rintf(q);
    int ia2 = (int)rintf((q - a1f) * 256.0f);
    ia2 = ia2 > 127 ? 127 : (ia2 < -127 ? -127 : ia2);
    const size_t o = (size_t)(c0 + oc) * R + r0 + x;
    A1[o] = (signed char)(int)a1f;
    A2[o] = (signed char)ia2;
  }
}

// ---------------------------------------------------------------------------
// transpose + cast: src R x C fp32 -> out C x R bf16 hi (V path weights)
// ---------------------------------------------------------------------------
__global__ void transpose_cast_k(const float* __restrict__ src, unsigned char* wsb,
                                 size_t oh, int R, int C) {
  __shared__ float t[32][33];
  unsigned char* ws = wsbase(wsb);
  short* OH = (short*)(ws + oh);
  const int c0 = blockIdx.x << 5, r0 = blockIdx.y << 5;
  const int x = threadIdx.x, y = threadIdx.y;
#pragma unroll
  for (int i = 0; i < 4; ++i) {
    const int rr = y + (i << 3);
    t[rr][x] = ntl(&src[(size_t)(r0 + rr) * C + c0 + x]);
  }
  __syncthreads();
#pragma unroll
  for (int i = 0; i < 4; ++i) {
    const int oc = y + (i << 3);
    OH[(size_t)(c0 + oc) * R + r0 + x] = f2bf(t[x][oc]);
  }
}

// ---------------------------------------------------------------------------
// 2-level i8 GEMM (round-9 core). STORE:
//  2 = fp32 TRANSPOSED ST[n][m] scratch, batched
//  4 = FUSED 2-level i8 out + per-(row,256col-tile) scales.
//      v2: rmax via LDS atomics (+__syncthreads for no-return-atomic drain),
//      then ONE quant pass with DIRECT nontemporal global byte stores —
//      no LDS data bounce (round-13's 8.4M bank conflicts removed).
// ---------------------------------------------------------------------------
DEV i32x4 mfma_i8(i32x4 a, i32x4 b, i32x4 c) {
  return __builtin_amdgcn_mfma_i32_16x16x64_i8(a, b, c, 0, 0, 0);
}
DEV i32x4 rfi8(const signed char* base, int lstride, int L, int row, int fg) {
  return *(const i32x4*)&base[L * lstride + row * 64 + ((fg ^ ((row >> 1) & 3)) << 4)];
}

template <bool RELU, int STORE>
__launch_bounds__(512, 2)
__global__ void gemm_i8_k(unsigned char* wsb,
                          size_t a1o, size_t a2o, size_t b1o, size_t b2o,
                          size_t aso, size_t bso, const float* __restrict__ bias,
                          size_t o0, size_t o1, size_t o2, int M, int N, int K,
                          int gx, int gxy, int grp) {
  __shared__ alignas(16) signed char lds8[114688];

  unsigned char* ws = wsbase(wsb);
  const int tid = threadIdx.x;
  const int lane = tid & 63;
  const int wave = tid >> 6;
  const int wm = (wave >> 2) << 6;   // 0 / 64
  const int wn = (wave & 3) << 6;    // 0 / 64 / 128 / 192
  const int fr = lane & 15;
  const int fg = lane >> 4;

  // bijective XCD swizzle (nwg multiple of 8) + grouped raster
  const int nwg = gridDim.x;
  const int q8 = nwg >> 3;
  const int id = (blockIdx.x & 7) * q8 + (blockIdx.x >> 3);
  const int bz = id / gxy;
  const int rem = id - bz * gxy;
  int by, bx;
  raster2d(rem, gx, grp, by, bx);
  const int brow = by << 7;    // 128-row tiles
  const int bcol = bx << 8;    // 256-col tiles

  const size_t batchA = (size_t)bz * M * K;
  const size_t batchB = (STORE == 2) ? (size_t)bz * N * K : 0;
  const signed char* Xa1 = (const signed char*)(ws + a1o) + batchA;
  const signed char* Xa2 = (const signed char*)(ws + a2o) + batchA;
  const signed char* Wa1 = (const signed char*)(ws + b1o) + batchB;
  const signed char* Wa2 = (const signed char*)(ws + b2o) + batchB;
  const float* AS = (const float*)(ws + aso) + (size_t)bz * M;
  const float* BS = (const float*)(ws + bso) + ((STORE == 2) ? (size_t)bz * N : 0);

  // staging source offsets (granule-swizzled, granule = 16 i8)
  const int ar = tid >> 2, ac = tid & 3;
  const size_t aOff = (size_t)(brow + ar) * K + ((ac ^ ((ar >> 1) & 3)) << 4);
  size_t bOff[2];
#pragma unroll
  for (int h = 0; h < 2; ++h) {
    const int G = tid + h * 512;
    const int r = G >> 2, c = G & 3;
    bOff[h] = (size_t)(bcol + r) * K + ((c ^ ((r >> 1) & 3)) << 4);
  }

  auto stageA = [&](int slotBase, int tt) {   // 2 gl16
    const int ko = tt * 64;
    gl16b(Xa1 + aOff + ko, &lds8[slotBase + (tid << 4)]);
    gl16b(Xa2 + aOff + ko, &lds8[slotBase + 8192 + (tid << 4)]);
  };
  auto stageB = [&](int slotBase, int tt) {   // 4 gl16
    const int ko = tt * 64;
#pragma unroll
    for (int h = 0; h < 2; ++h) {
      gl16b(Wa1 + bOff[h] + ko, &lds8[slotBase + ((tid + h * 512) << 4)]);
      gl16b(Wa2 + bOff[h] + ko, &lds8[slotBase + 16384 + ((tid + h * 512) << 4)]);
    }
  };

  const int nt = K / 64;
  i32x4 I1[4][4] = {};
  i32x4 I2[4][4] = {};

  // prologue: A0,B0,A1,B1
  stageA(0, 0);
  stageB(49152, 0);
  if (nt > 1) { stageA(16384, 1); stageB(49152 + 32768, 1); }
  if (nt > 1) { asm volatile("s_waitcnt vmcnt(6)" ::: "memory"); }
  else        { asm volatile("s_waitcnt vmcnt(0)" ::: "memory"); }
  __builtin_amdgcn_s_barrier();

  for (int t = 0; t < nt; ++t) {
    const signed char* aS = &lds8[(t % 3) * 16384];
    const signed char* bS = &lds8[49152 + (t & 1) * 32768];
    const int sA2 = ((t + 2) % 3) * 16384;
    const int sB2 = 49152 + (t & 1) * 32768;
    const bool pf = (t + 2 < nt);
    i32x4 bf[4][2], af[2][2];

    // ---- phase A: stage A(t+2); read all B frags + A rows 0-1; MFMA half 0 ----
    if (pf) stageA(sA2, t + 2);
#pragma unroll
    for (int j = 0; j < 4; ++j) {
      bf[j][0] = rfi8(bS, 16384, 0, wn + j * 16 + fr, fg);
      bf[j][1] = rfi8(bS, 16384, 1, wn + j * 16 + fr, fg);
    }
#pragma unroll
    for (int i = 0; i < 2; ++i) {
      af[i][0] = rfi8(aS, 8192, 0, wm + i * 16 + fr, fg);
      af[i][1] = rfi8(aS, 8192, 1, wm + i * 16 + fr, fg);
    }
    __builtin_amdgcn_s_setprio(1);
#pragma unroll
    for (int i = 0; i < 2; ++i)
#pragma unroll
      for (int j = 0; j < 4; ++j) {
        I1[i][j] = mfma_i8(af[i][0], bf[j][0], I1[i][j]);
        I2[i][j] = mfma_i8(af[i][0], bf[j][1], I2[i][j]);
        I2[i][j] = mfma_i8(af[i][1], bf[j][0], I2[i][j]);
      }
    __builtin_amdgcn_s_setprio(0);
    __builtin_amdgcn_s_barrier();

    // ---- phase B: stage B(t+2); read A rows 2-3; MFMA half 1; counted vmcnt ----
    asm volatile("" ::: "memory");
    if (pf) stageB(sB2, t + 2);
#pragma unroll
    for (int i = 0; i < 2; ++i) {
      af[i][0] = rfi8(aS, 8192, 0, wm + (2 + i) * 16 + fr, fg);
      af[i][1] = rfi8(aS, 8192, 1, wm + (2 + i) * 16 + fr, fg);
    }
    __builtin_amdgcn_s_setprio(1);
#pragma unroll
    for (int i = 0; i < 2; ++i)
#pragma unroll
      for (int j = 0; j < 4; ++j) {
        I1[2 + i][j] = mfma_i8(af[i][0], bf[j][0], I1[2 + i][j]);
        I2[2 + i][j] = mfma_i8(af[i][0], bf[j][1], I2[2 + i][j]);
        I2[2 + i][j] = mfma_i8(af[i][1], bf[j][0], I2[2 + i][j]);
      }
    __builtin_amdgcn_s_setprio(0);
    if (pf) { asm volatile("s_waitcnt vmcnt(6)" ::: "memory"); }
    else    { asm volatile("s_waitcnt vmcnt(0)" ::: "memory"); }
    __builtin_amdgcn_s_barrier();
  }

  const int fq4 = fg << 2;
  if constexpr (STORE == 4) {
    // ---- fused dequant + bias(+relu) + per-tile-row quant, DIRECT stores ----
    signed char* O1 = (signed char*)(ws + o0);
    signed char* O2 = (signed char*)(ws + o1);
    float* TS = (float*)(ws + o2);
    const int nblk = N >> 8;
    unsigned int* rmaxU = (unsigned int*)lds8;
    float* rmaxF = (float*)rmaxU;
    if (tid < 128) rmaxU[tid] = 0;
    __syncthreads();                      // drain init before atomics
    float sbj[4], bvj[4];
#pragma unroll
    for (int j = 0; j < 4; ++j) {
      const int cl = wn + j * 16 + fr;
      sbj[j] = BS[bcol + cl];
      bvj[j] = bias ? bias[bcol + cl] : 0.0f;
    }
    // pass 1: row maxima (within this 256-col tile)
#pragma unroll
    for (int i = 0; i < 4; ++i) {
      const int rl = wm + i * 16 + fq4;
      const f32x4 sa4 = *(const f32x4*)&AS[brow + rl];
      float mx[4] = {0.0f, 0.0f, 0.0f, 0.0f};
#pragma unroll
      for (int j = 0; j < 4; ++j)
#pragma unroll
        for (int e = 0; e < 4; ++e) {
          float u = ((float)I1[i][j][e] + (float)I2[i][j][e] * (1.0f / 256.0f)) *
                        (sa4[e] * sbj[j]) + bvj[j];
          if (RELU) u = fmaxf(u, 0.0f);
          mx[e] = fmaxf(mx[e], fabsf(u));
        }
#pragma unroll
      for (int e = 0; e < 4; ++e)
        atomicMax(&rmaxU[rl + e], __float_as_uint(mx[e]));
    }
    __syncthreads();                      // drain NO-RETURN atomics
    if (tid < 128)
      TS[(size_t)(brow + tid) * nblk + (bcol >> 8)] = rmaxF[tid] * (1.0f / 127.0f);
    float invv[4][4];
#pragma unroll
    for (int i = 0; i < 4; ++i)
#pragma unroll
      for (int e = 0; e < 4; ++e) {
        const float rm = rmaxF[wm + i * 16 + fq4 + e];
        invv[i][e] = (rm > 1e-30f) ? 127.0f / rm : 0.0f;
      }
    // pass 2 (single): quantize both levels, direct NT byte stores.
    // Per instruction a wave writes 4 rows x 16B contiguous; j-loop completes
    // 64B runs per row -> L2 merges to full write granules.
#pragma unroll
    for (int i = 0; i < 4; ++i) {
      const int rl = wm + i * 16 + fq4;
      const f32x4 sa4 = *(const f32x4*)&AS[brow + rl];
#pragma unroll
      for (int j = 0; j < 4; ++j) {
        const int cl = wn + j * 16 + fr;
#pragma unroll
        for (int e = 0; e < 4; ++e) {
          float u = ((float)I1[i][j][e] + (float)I2[i][j][e] * (1.0f / 256.0f)) *
                        (sa4[e] * sbj[j]) + bvj[j];
          if (RELU) u = fmaxf(u, 0.0f);
          const float q = u * invv[i][e];
          const float n1 = rintf(q);
          int i2 = (int)rintf((q - n1) * 256.0f);
          i2 = i2 > 127 ? 127 : (i2 < -127 ? -127 : i2);
          const size_t go = (size_t)(brow + rl + e) * N + bcol + cl;
          nts((signed char)(int)n1, &O1[go]);
          nts((signed char)i2, &O2[go]);
        }
      }
    }
  } else {
    // ---- STORE == 2: dequant -> fp32 TRANSPOSED ST[n][m] (batched) ----
    float* Of = (float*)(ws + o0) + (size_t)bz * M * N;
    float* ldsf = (float*)lds8;
#pragma unroll
    for (int h2 = 0; h2 < 2; ++h2) {
      __syncthreads();
      if ((wn >> 7) == h2) {
#pragma unroll
        for (int i = 0; i < 4; ++i) {
          const int rl = wm + i * 16 + fq4;
          const f32x4 sa4 = *(const f32x4*)&AS[brow + rl];
#pragma unroll
          for (int j = 0; j < 4; ++j) {
            const int cp = (wn & 127) + j * 16 + fr;
            const float sb = BS[bcol + wn + j * 16 + fr];
            f32x4 u;
#pragma unroll
            for (int e = 0; e < 4; ++e)
              u[e] = ((float)I1[i][j][e] + (float)I2[i][j][e] * (1.0f / 256.0f)) *
                     (sa4[e] * sb);
            *(f32x4*)&ldsf[cp * 132 + rl] = u;
          }
        }
      }
      __syncthreads();
#pragma unroll
      for (int gi = 0; gi < 8; ++gi) {
        const int g = gi * 512 + tid;
        const int tr = g >> 5, tc4 = (g & 31) << 2;
        const f32x4 v = *(const f32x4*)&ldsf[tr * 132 + tc4];
        nts(v, (f32x4*)&Of[(size_t)(bcol + h2 * 128 + tr) * M + brow + tc4]);
      }
    }
  }
}

// ---------------------------------------------------------------------------
// 256x256-tile 8-wave pipelined bf16 GEMM + grouped raster (round-9 core).
// STORE: 1 bf16 out, 3 fp32 optr bounce.
// ---------------------------------------------------------------------------
constexpr int CH = 8192;        // shorts per 16KB chunk

DEV short8 read_frag1(const short* base, int row, int s, int fg) {
  return *(const short8*)&base[row * 64 + ((((s << 2) | fg) ^ (row & 7)) << 3)];
}

DEV f32x4 mfma16(short8 a, short8 b, f32x4 c) {
  return __builtin_amdgcn_mfma_f32_16x16x32_bf16(a, b, c, 0, 0, 0);
}

template <bool RELU, int STORE>
__launch_bounds__(512, 2)
__global__ void gemm8_k(unsigned char* wsb,
                        size_t aoff0, size_t boff0,
                        const float* __restrict__ bias,
                        size_t ooff0, float* __restrict__ optr,
                        int M, int N, int K, int gx, int gxy, int grp) {
  __shared__ alignas(16) short lds[10 * CH];

  unsigned char* ws = wsbase(wsb);
  const int tid = threadIdx.x;
  const int lane = tid & 63;
  const int wave = tid >> 6;
  const int wm = (wave >> 2) << 7;   // 0 / 128
  const int wn = (wave & 3) << 6;    // 0 / 64 / 128 / 192

  const int nwg = gridDim.x;
  const int q8 = nwg >> 3;
  const int id = (blockIdx.x & 7) * q8 + (blockIdx.x >> 3);
  const int bz = id / gxy;
  const int rem = id - bz * gxy;
  int by, bx;
  raster2d(rem, gx, grp, by, bx);
  const int brow = by << 8;
  const int bcol = bx << 8;

  const short* A0 = (const short*)(ws + aoff0) + (size_t)bz * M * K;
  const short* B0g = (const short*)(ws + boff0) + (size_t)bz * N * K;

  size_t aSrc[2][2], bSrc[2][2];
#pragma unroll
  for (int h = 0; h < 2; ++h) {
    const int G = tid + h * 512;
    const int r = G >> 3, c = G & 7;
#pragma unroll
    for (int qq = 0; qq < 2; ++qq) {
      aSrc[qq][h] = (size_t)(brow + qq * 128 + r) * K + (size_t)((c ^ (r & 7)) << 3);
      bSrc[qq][h] = (size_t)(bcol + qq * 128 + r) * K + (size_t)((c ^ (r & 7)) << 3);
    }
  }
  const int ldst0 = tid << 3;

  auto issueA = [&](int slot, int qq, int tt) {
    short* dst = &lds[slot + qq * CH];
    const size_t ka = (size_t)tt * 64;
    gl16(A0 + aSrc[qq][0] + ka, dst + ldst0);
    gl16(A0 + aSrc[qq][1] + ka, dst + ldst0 + CH / 2);
  };
  auto issueB = [&](int slot, int qq, int tt) {
    short* dst = &lds[slot + qq * CH];
    const size_t ka = (size_t)tt * 64;
    gl16(B0g + bSrc[qq][0] + ka, dst + ldst0);
    gl16(B0g + bSrc[qq][1] + ka, dst + ldst0 + CH / 2);
  };

  const int nt = K / 64;
  const int fr = lane & 15;
  const int fg = lane >> 4;

  f32x4 acc[8][4] = {};

  issueA(0, 0, 0); issueA(0, 1, 0);
  issueB(6 * CH, 0, 0); issueB(6 * CH, 1, 0);
  if (nt > 1) {
    issueA(2 * CH, 0, 1); issueA(2 * CH, 1, 1);
    issueB(8 * CH, 0, 1); issueB(8 * CH, 1, 1);
    asm volatile("s_waitcnt vmcnt(8)" ::: "memory");
  } else {
    asm volatile("s_waitcnt vmcnt(0)" ::: "memory");
  }
  __builtin_amdgcn_s_barrier();

  for (int t = 0; t < nt; ++t) {
    const short* aBase = &lds[(t % 3) * (2 * CH)];
    const short* bBase = &lds[6 * CH + (t & 1) * (2 * CH)];
    const int sA2 = ((t + 2) % 3) * (2 * CH);
    const int sB  = 6 * CH + (t & 1) * (2 * CH);
    const bool pf = (t + 2 < nt);
    short8 bfr[4][2], av[4][2];

    if (pf) { issueA(sA2, 0, t + 2); issueA(sA2, 1, t + 2); }
#pragma unroll
    for (int j = 0; j < 4; ++j) {
      bfr[j][0] = read_frag1(bBase, wn + j * 16 + fr, 0, fg);
      bfr[j][1] = read_frag1(bBase, wn + j * 16 + fr, 1, fg);
    }
#pragma unroll
    for (int i = 0; i < 4; ++i) {
      av[i][0] = read_frag1(aBase, wm + i * 16 + fr, 0, fg);
      av[i][1] = read_frag1(aBase, wm + i * 16 + fr, 1, fg);
    }
    __builtin_amdgcn_s_setprio(1);
#pragma unroll
    for (int i = 0; i < 4; ++i)
#pragma unroll
      for (int j = 0; j < 4; ++j) {
        acc[i][j] = mfma16(av[i][0], bfr[j][0], acc[i][j]);
        acc[i][j] = mfma16(av[i][1], bfr[j][1], acc[i][j]);
      }
    __builtin_amdgcn_s_setprio(0);
    __builtin_amdgcn_s_barrier();

    asm volatile("" ::: "memory");
    if (pf) { issueB(sB, 0, t + 2); issueB(sB, 1, t + 2); }
#pragma unroll
    for (int i = 0; i < 4; ++i) {
      av[i][0] = read_frag1(aBase, wm + 64 + i * 16 + fr, 0, fg);
      av[i][1] = read_frag1(aBase, wm + 64 + i * 16 + fr, 1, fg);
    }
    __builtin_amdgcn_s_setprio(1);
#pragma unroll
    for (int i = 0; i < 4; ++i)
#pragma unroll
      for (int j = 0; j < 4; ++j) {
        acc[4 + i][j] = mfma16(av[i][0], bfr[j][0], acc[4 + i][j]);
        acc[4 + i][j] = mfma16(av[i][1], bfr[j][1], acc[4 + i][j]);
      }
    __builtin_amdgcn_s_setprio(0);
    if (pf) {
      asm volatile("s_waitcnt vmcnt(8)" ::: "memory");
    } else {
      asm volatile("s_waitcnt vmcnt(0)" ::: "memory");
    }
    __builtin_amdgcn_s_barrier();
  }

  // ---- epilogue ----
  const int fq4 = (lane >> 4) << 2;
  if constexpr (STORE == 1) {
    short* Oh = (short*)(ws + ooff0);
    __syncthreads();
#pragma unroll
    for (int i = 0; i < 8; ++i) {
      const int rl = wm + i * 16 + fq4;
#pragma unroll
      for (int j = 0; j < 4; ++j) {
        const int cl = wn + j * 16 + fr;
        const float bv = bias ? bias[bcol + cl] : 0.0f;
#pragma unroll
        for (int e = 0; e < 4; ++e) {
          float u = acc[i][j][e] + bv;
          if (RELU) u = fmaxf(u, 0.0f);
          lds[(rl + e) * 264 + cl] = f2bf(u);
        }
      }
    }
    __syncthreads();
#pragma unroll
    for (int gi = 0; gi < 16; ++gi) {
      const int g = gi * 512 + tid;
      const int row = g >> 5, cg = g & 31;
      const short8 v = *(const short8*)&lds[row * 264 + cg * 8];
      nts(v, (short8*)&Oh[(size_t)(brow + row) * N + bcol + cg * 8]);
    }
  } else {
    float* Op = optr + (size_t)bz * M * N;
    float* ldsf = (float*)lds;
#pragma unroll
    for (int h = 0; h < 2; ++h) {
      __syncthreads();
      if ((wm & 128) == (h << 7)) {
#pragma unroll
        for (int i = 0; i < 8; ++i) {
          const int rp = (wm & 127) + i * 16 + fq4;
#pragma unroll
          for (int j = 0; j < 4; ++j) {
            const int cl = wn + j * 16 + fr;
#pragma unroll
            for (int e = 0; e < 4; ++e)
              ldsf[(rp + e) * 258 + cl] = acc[i][j][e];
          }
        }
      }
      __syncthreads();
#pragma unroll
      for (int gi = 0; gi < 16; ++gi) {
        const int g = gi * 512 + tid;
        const int tr = g >> 6, tc4 = (g & 63) << 2;
        const f32x4 v = *(const f32x4*)&ldsf[tr * 258 + tc4];
        nts(v, (f32x4*)&Op[(size_t)(brow + h * 128 + tr) * N + bcol + tc4]);
      }
    }
  }
}

// ---------------------------------------------------------------------------
// row softmax over ST rows (axis-1 softmax of scores), output bf16 probs^T
// ---------------------------------------------------------------------------
__launch_bounds__(256)
__global__ void softmax_rows_k(unsigned char* wsb, size_t st, size_t pt) {
  constexpr int S = 2048;
  unsigned char* ws = wsbase(wsb);
  const f32x4* row = (const f32x4*)((const float*)(ws + st) + (size_t)blockIdx.x * S);
  short4v* out = (short4v*)((short*)(ws + pt) + (size_t)blockIdx.x * S);
  const int tid = threadIdx.x, lane = tid & 63, wv = tid >> 6;
  const f32x4 a = ntl(&row[tid]);
  const f32x4 b = ntl(&row[tid + 256]);
  float m = fmaxf(fmaxf(fmaxf(a[0], a[1]), fmaxf(a[2], a[3])),
                  fmaxf(fmaxf(b[0], b[1]), fmaxf(b[2], b[3])));
#pragma unroll
  for (int o = 32; o; o >>= 1) m = fmaxf(m, __shfl_xor(m, o));
  __shared__ float rb[8];
  if (lane == 0) rb[wv] = m;
  __syncthreads();
  m = fmaxf(fmaxf(rb[0], rb[1]), fmaxf(rb[2], rb[3]));
  float e[8];
  float s = 0.0f;
#pragma unroll
  for (int q = 0; q < 4; ++q) { e[q] = expf(a[q] - m); s += e[q]; }
#pragma unroll
  for (int q = 0; q < 4; ++q) { e[4 + q] = expf(b[q] - m); s += e[4 + q]; }
#pragma unroll
  for (int o = 32; o; o >>= 1) s += __shfl_xor(s, o);
  if (lane == 0) rb[4 + wv] = s;
  __syncthreads();
  s = rb[4] + rb[5] + rb[6] + rb[7];
  const float inv = 1.0f / s;
  short4v o1, o2;
#pragma unroll
  for (int q = 0; q < 4; ++q) { o1[q] = f2bf(e[q] * inv); o2[q] = f2bf(e[4 + q] * inv); }
  nts(o1, &out[tid]);
  nts(o2, &out[tid + 256]);
}

// ---------------------------------------------------------------------------
extern "C" void kernel_launch(void* const* d_in, const int* in_sizes, int n_in,
                              void* d_out, int out_size, void* d_ws, size_t ws_size,
                              hipStream_t stream) {
  const float* x   = (const float*)d_in[0];
  const float* qw1 = (const float*)d_in[1];
  const float* qb1 = (const float*)d_in[2];
  const float* qw2 = (const float*)d_in[3];
  const float* qb2 = (const float*)d_in[4];
  const float* kw1 = (const float*)d_in[5];
  const float* kb1 = (const float*)d_in[6];
  const float* kw2 = (const float*)d_in[7];
  const float* kb2 = (const float*)d_in[8];
  const float* vw1 = (const float*)d_in[9];
  const float* vb1 = (const float*)d_in[10];
  const float* vw2 = (const float*)d_in[11];
  const float* vb2 = (const float*)d_in[12];
  float* out = (float*)d_out;
  unsigned char* wsb = (ws_size >= WS_TOTAL) ? (unsigned char*)d_ws : nullptr;
  unsigned char* wsr;
  if (wsb) wsr = wsb;
  else { hipError_t e = hipGetSymbolAddress((void**)&wsr, HIP_SYMBOL(g_ws)); (void)e; }

  const int M = BB * SS;  // 8192
  dim3 blk(512);
  dim3 tb(32, 8);

  // x -> i8 2-level (Q/K MLP1) and bf16 hi (V MLP1)
  quant_x_k<<<8192, 256, 0, stream>>>(x, wsb, OFF_XA1, OFF_XA2, OFF_XS);
  cast_hi_k<<<4096, 256, 0, stream>>>(x, wsb, OFF_XH, NX / 4);

  // ================= Q path (i8, fused quant epilogues) =================
  hipMemsetAsync(wsr + OFF_CM, 0, 32768, stream);
  colmax_k<<<dim3(HHID / 256, DD / 128), 256, 0, stream>>>(qw1, wsb, OFF_CM, DD, HHID);
  scalefix_k<<<32, 256, 0, stream>>>(wsb, OFF_CM, HHID);
  transpose_quant_k<<<dim3(HHID / 32, DD / 32), tb, 0, stream>>>(qw1, wsb, OFF_WA1, OFF_WA2, OFF_CM, DD, HHID);
  gemm_i8_k<true, 4><<<2048, blk, 0, stream>>>(wsb, OFF_XA1, OFF_XA2, OFF_WA1, OFF_WA2,
                                               OFF_XS, OFF_CM, qb1, OFF_HA1, OFF_HA2, OFF_TSH,
                                               M, HHID, DD, 32, 2048, 8);
  rescale_k<<<8192, 256, 0, stream>>>(wsb, OFF_HA1, OFF_HA2, OFF_TSH, OFF_HS, HHID);
  hipMemsetAsync(wsr + OFF_CM, 0, 32768, stream);
  colmax_k<<<dim3(DD / 256, HHID / 128), 256, 0, stream>>>(qw2, wsb, OFF_CM, HHID, DD);
  scalefix_k<<<8, 256, 0, stream>>>(wsb, OFF_CM, DD);
  transpose_quant_k<<<dim3(DD / 32, HHID / 32), tb, 0, stream>>>(qw2, wsb, OFF_WA1, OFF_WA2, OFF_CM, HHID, DD);
  gemm_i8_k<false, 4><<<512, blk, 0, stream>>>(wsb, OFF_HA1, OFF_HA2, OFF_WA1, OFF_WA2,
                                               OFF_HS, OFF_CM, qb2, OFF_QA1, OFF_QA2, OFF_TSQ,
                                               M, DD, HHID, 8, 512, 8);
  rescale_k<<<8192, 256, 0, stream>>>(wsb, OFF_QA1, OFF_QA2, OFF_TSQ, OFF_QS, DD);

  // ================= K path =================
  hipMemsetAsync(wsr + OFF_CM, 0, 32768, stream);
  colmax_k<<<dim3(HHID / 256, DD / 128), 256, 0, stream>>>(kw1, wsb, OFF_CM, DD, HHID);
  scalefix_k<<<32, 256, 0, stream>>>(wsb, OFF_CM, HHID);
  transpose_quant_k<<<dim3(HHID / 32, DD / 32), tb, 0, stream>>>(kw1, wsb, OFF_WA1, OFF_WA2, OFF_CM, DD, HHID);
  gemm_i8_k<true, 4><<<2048, blk, 0, stream>>>(wsb, OFF_XA1, OFF_XA2, OFF_WA1, OFF_WA2,
                                               OFF_XS, OFF_CM, kb1, OFF_HA1, OFF_HA2, OFF_TSH,
                                               M, HHID, DD, 32, 2048, 8);
  rescale_k<<<8192, 256, 0, stream>>>(wsb, OFF_HA1, OFF_HA2, OFF_TSH, OFF_HS, HHID);
  hipMemsetAsync(wsr + OFF_CM, 0, 32768, stream);
  colmax_k<<<dim3(DD / 256, HHID / 128), 256, 0, stream>>>(kw2, wsb, OFF_CM, HHID, DD);
  scalefix_k<<<8, 256, 0, stream>>>(wsb, OFF_CM, DD);
  transpose_quant_k<<<dim3(DD / 32, HHID / 32), tb, 0, stream>>>(kw2, wsb, OFF_WA1, OFF_WA2, OFF_CM, HHID, DD);
  gemm_i8_k<false, 4><<<512, blk, 0, stream>>>(wsb, OFF_HA1, OFF_HA2, OFF_WA1, OFF_WA2,
                                               OFF_HS, OFF_CM, kb2, OFF_KA1, OFF_KA2, OFF_TSQ,
                                               M, DD, HHID, 8, 512, 8);
  rescale_k<<<8192, 256, 0, stream>>>(wsb, OFF_KA1, OFF_KA2, OFF_TSQ, OFF_KS, DD);

  // ================= V path (plain bf16) =================
  transpose_cast_k<<<dim3(HHID / 32, DD / 32), tb, 0, stream>>>(vw1, wsb, OFF_WHV, DD, HHID);
  gemm8_k<true, 1><<<1024, blk, 0, stream>>>(
      wsb, OFF_XH, OFF_WHV, vb1, OFF_HH, nullptr, M, HHID, DD, 32, 1024, 4);
  transpose_cast_k<<<dim3(DD / 32, HHID / 32), tb, 0, stream>>>(vw2, wsb, OFF_WHV, HHID, DD);
  gemm8_k<false, 1><<<256, blk, 0, stream>>>(
      wsb, OFF_HH, OFF_WHV, vb2, OFF_V, nullptr, M, DD, HHID, 8, 256, 4);

  // ---- scores^T (i8, batched): ST[t][s] per batch ----
  gemm_i8_k<false, 2><<<512, blk, 0, stream>>>(wsb, OFF_QA1, OFF_QA2, OFF_KA1, OFF_KA2,
                                               OFF_QS, OFF_KS, nullptr, OFF_ST, 0, 0,
                                               SS, SS, DD, 8, 128, 8);

  // ---- softmax over axis 1 == row softmax of ST; writes bf16 probs^T ----
  softmax_rows_k<<<BB * SS, 256, 0, stream>>>(wsb, OFF_ST, OFF_PT);

  // ---- out = V @ probs (B^T = probs^T), fp32 to d_out ----
  gemm8_k<false, 3><<<256, blk, 0, stream>>>(
      wsb, OFF_V, OFF_PT, nullptr, 0, out, SS, SS, DD, 8, 64, 4);
}

// Round 15
// 2672.473 us; speedup vs baseline: 1.1574x; 1.1574x over previous
//
#include <hip/hip_runtime.h>
#include <cstdint>
#include <cstddef>

typedef __attribute__((ext_vector_type(8))) short short8;
typedef __attribute__((ext_vector_type(4))) short short4v;
typedef __attribute__((ext_vector_type(4))) float f32x4;
typedef __attribute__((ext_vector_type(4))) int i32x4;

#define DEV __device__ __forceinline__

// Problem geometry (fixed by the reference)
constexpr int DD = 2048;           // D
constexpr int HHID = 8192;         // H
constexpr int BB = 4;              // B
constexpr int SS = 2048;           // S
constexpr size_t NX = (size_t)BB * SS * DD;   // 16,777,216
constexpr size_t NW = (size_t)DD * HHID;      // 16,777,216
constexpr size_t NH = (size_t)BB * SS * HHID; // 67,108,864

// Scratch layout (bytes) — round-9 layout
constexpr size_t OFF_XH  = 0;                    // x bf16 hi (V path)
constexpr size_t OFF_XA1 = OFF_XH + NX * 2;      // x i8 lvl1
constexpr size_t OFF_XA2 = OFF_XA1 + NX;         // x i8 lvl2
constexpr size_t OFF_WA1 = OFF_XA2 + NX;         // weight i8 lvl1 (reused 4x)
constexpr size_t OFF_WA2 = OFF_WA1 + NW;         // weight i8 lvl2
constexpr size_t OFF_WHV = OFF_WA1;              // alias: V-path bf16 weights
constexpr size_t OFF_HH  = OFF_WA2 + NW;         // h bf16 hi / ST alias
constexpr size_t OFF_HL  = OFF_HH + NH * 2;      // h bf16 lo / PT alias
constexpr size_t OFF_QKH = OFF_HL + NH * 2;      // Q-then-K split hi (reused)
constexpr size_t OFF_QKL = OFF_QKH + NX * 2;
constexpr size_t OFF_QA1 = OFF_QKL + NX * 2;     // Q i8
constexpr size_t OFF_QA2 = OFF_QA1 + NX;
constexpr size_t OFF_KA1 = OFF_QA2 + NX;         // K i8
constexpr size_t OFF_KA2 = OFF_KA1 + NX;
constexpr size_t OFF_HA1 = OFF_KA2 + NX;         // h i8 (reused Q/K paths)
constexpr size_t OFF_HA2 = OFF_HA1 + NH;
constexpr size_t OFF_V   = OFF_HA2 + NH;         // V bf16
constexpr size_t OFF_XS  = OFF_V + NX * 2;       // f32[8192] x row scales
constexpr size_t OFF_HS  = OFF_XS + 32768;       // f32[8192] h row scales
constexpr size_t OFF_QS  = OFF_HS + 32768;       // f32[8192] Q row scales
constexpr size_t OFF_KS  = OFF_QS + 32768;       // f32[8192] K row scales
constexpr size_t OFF_CM  = OFF_KS + 32768;       // colmax scratch (reused 4x)
constexpr size_t WS_TOTAL = OFF_CM + 32768;
constexpr size_t OFF_ST = OFF_HH;                // fp32 scores^T
constexpr size_t OFF_PT = OFF_HL;                // bf16 probs^T

__device__ __align__(256) unsigned char g_ws[WS_TOTAL];

DEV unsigned char* wsbase(unsigned char* p) { return p ? p : (unsigned char*)g_ws; }
DEV short f2bf(float v) { __bf16 b = (__bf16)v; return __builtin_bit_cast(short, b); }
DEV float bf2f(short s) { return (float)__builtin_bit_cast(__bf16, s); }

template <typename T> DEV void nts(T v, T* p) { __builtin_nontemporal_store(v, p); }
template <typename T> DEV T ntl(const T* p) { return __builtin_nontemporal_load(p); }

DEV void gl16(const short* g, short* l) {
  __builtin_amdgcn_global_load_lds((const __attribute__((address_space(1))) void*)g,
                                   (__attribute__((address_space(3))) void*)l, 16, 0, 0);
}
DEV void gl16b(const signed char* g, signed char* l) {
  __builtin_amdgcn_global_load_lds((const __attribute__((address_space(1))) void*)g,
                                   (__attribute__((address_space(3))) void*)l, 16, 0, 0);
}

// grouped-row raster: concurrently-resident blocks form a 2D window in L2
DEV void raster2d(int rem, int gx, int grp, int& by, int& bx) {
  const int tpg = grp * gx;
  const int gidx = rem / tpg;
  const int o = rem - gidx * tpg;
  const int r = o / grp;
  by = gidx * grp + (o - r * grp);
  bx = r;
}

// ---------------------------------------------------------------------------
// cast x -> bf16 hi (V path)
// ---------------------------------------------------------------------------
__global__ void cast_hi_k(const float* __restrict__ x, unsigned char* wsb,
                          size_t oh, size_t n4) {
  unsigned char* ws = wsbase(wsb);
  short4v* OH = (short4v*)(ws + oh);
  const f32x4* X = (const f32x4*)x;
  for (size_t i = (size_t)blockIdx.x * blockDim.x + threadIdx.x; i < n4;
       i += (size_t)gridDim.x * blockDim.x) {
    const f32x4 v = ntl(&X[i]);
    short4v hs;
#pragma unroll
    for (int e = 0; e < 4; ++e) hs[e] = f2bf(v[e]);
    OH[i] = hs;
  }
}

// ---------------------------------------------------------------------------
// per-row 2-level i8 quantization of fp32 x (rowlen 2048)
// ---------------------------------------------------------------------------
__launch_bounds__(256)
__global__ void quant_x_k(const float* __restrict__ x, unsigned char* wsb,
                          size_t oa1, size_t oa2, size_t oxs) {
  unsigned char* ws = wsbase(wsb);
  signed char* A1 = (signed char*)(ws + oa1);
  signed char* A2 = (signed char*)(ws + oa2);
  float* XS = (float*)(ws + oxs);
  const int row = blockIdx.x;
  const float* xr = x + (size_t)row * 2048;
  const int tid = threadIdx.x, lane = tid & 63;
  const f32x4 v0 = *(const f32x4*)&xr[tid * 8];
  const f32x4 v1 = *(const f32x4*)&xr[tid * 8 + 4];
  float m = 0.0f;
#pragma unroll
  for (int e = 0; e < 4; ++e) m = fmaxf(m, fmaxf(fabsf(v0[e]), fabsf(v1[e])));
#pragma unroll
  for (int o = 32; o; o >>= 1) m = fmaxf(m, __shfl_xor(m, o));
  __shared__ float rb[4];
  if (lane == 0) rb[tid >> 6] = m;
  __syncthreads();
  m = fmaxf(fmaxf(rb[0], rb[1]), fmaxf(rb[2], rb[3]));
  const float inv = (m > 1e-30f) ? 127.0f / m : 0.0f;
  if (tid == 0) XS[row] = m * (1.0f / 127.0f);
  unsigned int w1a = 0, w1b = 0, w2a = 0, w2b = 0;
#pragma unroll
  for (int e = 0; e < 8; ++e) {
    const float xv = (e < 4) ? v0[e] : v1[e - 4];
    const float q = xv * inv;
    const float a1f = rintf(q);
    int ia2 = (int)rintf((q - a1f) * 256.0f);
    ia2 = ia2 > 127 ? 127 : (ia2 < -127 ? -127 : ia2);
    const unsigned int b1 = (unsigned char)(signed char)(int)a1f;
    const unsigned int b2 = (unsigned char)(signed char)ia2;
    if (e < 4) { w1a |= b1 << (8 * e); w2a |= b2 << (8 * e); }
    else       { w1b |= b1 << (8 * (e - 4)); w2b |= b2 << (8 * (e - 4)); }
  }
  const size_t o = (size_t)row * 2048 + tid * 8;
  *(unsigned int*)&A1[o] = w1a; *(unsigned int*)&A1[o + 4] = w1b;
  *(unsigned int*)&A2[o] = w2a; *(unsigned int*)&A2[o + 4] = w2b;
}

// ---------------------------------------------------------------------------
// per-row 2-level i8 quantization of split-bf16 (hi+lo) matrix rows
// ---------------------------------------------------------------------------
__launch_bounds__(1024)
__global__ void rowquant_k(unsigned char* wsb, size_t hho, size_t hlo,
                           size_t oa1, size_t oa2, size_t oso, int rowlen) {
  unsigned char* ws = wsbase(wsb);
  const int row = blockIdx.x, tid = threadIdx.x, lane = tid & 63, wv = tid >> 6;
  const int nw = blockDim.x >> 6;
  const short8 hi = ntl((const short8*)((const short*)(ws + hho) + (size_t)row * rowlen) + tid);
  const short8 lo = ntl((const short8*)((const short*)(ws + hlo) + (size_t)row * rowlen) + tid);
  float v[8]; float m = 0.0f;
#pragma unroll
  for (int e = 0; e < 8; ++e) {
    v[e] = bf2f(hi[e]) + bf2f(lo[e]);
    m = fmaxf(m, fabsf(v[e]));
  }
#pragma unroll
  for (int o = 32; o; o >>= 1) m = fmaxf(m, __shfl_xor(m, o));
  __shared__ float rb[16];
  if (lane == 0) rb[wv] = m;
  __syncthreads();
  m = rb[0];
  for (int i = 1; i < nw; ++i) m = fmaxf(m, rb[i]);
  const float inv = (m > 1e-30f) ? 127.0f / m : 0.0f;
  if (tid == 0) ((float*)(ws + oso))[row] = m * (1.0f / 127.0f);
  unsigned int w1a = 0, w1b = 0, w2a = 0, w2b = 0;
#pragma unroll
  for (int e = 0; e < 8; ++e) {
    const float q = v[e] * inv;
    const float a1f = rintf(q);
    int ia2 = (int)rintf((q - a1f) * 256.0f);
    ia2 = ia2 > 127 ? 127 : (ia2 < -127 ? -127 : ia2);
    const unsigned int b1 = (unsigned char)(signed char)(int)a1f;
    const unsigned int b2 = (unsigned char)(signed char)ia2;
    if (e < 4) { w1a |= b1 << (8 * e); w2a |= b2 << (8 * e); }
    else       { w1b |= b1 << (8 * (e - 4)); w2b |= b2 << (8 * (e - 4)); }
  }
  const size_t o = (size_t)row * rowlen + tid * 8;
  signed char* A1 = (signed char*)(ws + oa1);
  signed char* A2 = (signed char*)(ws + oa2);
  *(unsigned int*)&A1[o] = w1a; *(unsigned int*)&A1[o + 4] = w1b;
  *(unsigned int*)&A2[o] = w2a; *(unsigned int*)&A2[o + 4] = w2b;
}

// ---------------------------------------------------------------------------
// per-column absmax of w [R][C] -> MX[col]
// ---------------------------------------------------------------------------
__launch_bounds__(256)
__global__ void colmax_k(const float* __restrict__ w, unsigned char* wsb,
                         size_t omax, int R, int C) {
  unsigned char* ws = wsbase(wsb);
  unsigned int* MX = (unsigned int*)(ws + omax);
  const int col = blockIdx.x * 256 + threadIdx.x;
  const int r0 = blockIdx.y * 128;
  float m = 0.0f;
  for (int r = 0; r < 128; ++r) m = fmaxf(m, fabsf(w[(size_t)(r0 + r) * C + col]));
  atomicMax(&MX[col], __float_as_uint(m));
}

// in-place: uint-encoded absmax -> f32 scale (max/127)
__global__ void scalefix_k(unsigned char* wsb, size_t off, int n) {
  unsigned char* ws = wsbase(wsb);
  const int i = blockIdx.x * 256 + threadIdx.x;
  if (i < n) {
    float* p = (float*)(ws + off);
    const unsigned int u = ((const unsigned int*)p)[i];
    p[i] = __uint_as_float(u) * (1.0f / 127.0f);
  }
}

// ---------------------------------------------------------------------------
// transpose + 2-level i8 quant: src R x C fp32 -> a1,a2 [C][R] i8
// ---------------------------------------------------------------------------
__global__ void transpose_quant_k(const float* __restrict__ src, unsigned char* wsb,
                                  size_t oa1, size_t oa2, size_t osc, int R, int C) {
  __shared__ float t[32][33];
  unsigned char* ws = wsbase(wsb);
  signed char* A1 = (signed char*)(ws + oa1);
  signed char* A2 = (signed char*)(ws + oa2);
  const float* SC = (const float*)(ws + osc);
  const int c0 = blockIdx.x << 5, r0 = blockIdx.y << 5;
  const int x = threadIdx.x, y = threadIdx.y;
#pragma unroll
  for (int i = 0; i < 4; ++i) {
    const int rr = y + (i << 3);
    t[rr][x] = ntl(&src[(size_t)(r0 + rr) * C + c0 + x]);
  }
  __syncthreads();
#pragma unroll
  for (int i = 0; i < 4; ++i) {
    const int oc = y + (i << 3);
    const float v = t[x][oc];
    const float s = SC[c0 + oc];
    const float inv = (s > 1e-38f) ? 1.0f / s : 0.0f;
    const float q = v * inv;
    const float a1f = rintf(q);
    int ia2 = (int)rintf((q - a1f) * 256.0f);
    ia2 = ia2 > 127 ? 127 : (ia2 < -127 ? -127 : ia2);
    const size_t o = (size_t)(c0 + oc) * R + r0 + x;
    A1[o] = (signed char)(int)a1f;
    A2[o] = (signed char)ia2;
  }
}

// ---------------------------------------------------------------------------
// transpose + cast: src R x C fp32 -> out C x R bf16 hi (V path weights)
// ---------------------------------------------------------------------------
__global__ void transpose_cast_k(const float* __restrict__ src, unsigned char* wsb,
                                 size_t oh, int R, int C) {
  __shared__ float t[32][33];
  unsigned char* ws = wsbase(wsb);
  short* OH = (short*)(ws + oh);
  const int c0 = blockIdx.x << 5, r0 = blockIdx.y << 5;
  const int x = threadIdx.x, y = threadIdx.y;
#pragma unroll
  for (int i = 0; i < 4; ++i) {
    const int rr = y + (i << 3);
    t[rr][x] = ntl(&src[(size_t)(r0 + rr) * C + c0 + x]);
  }
  __syncthreads();
#pragma unroll
  for (int i = 0; i < 4; ++i) {
    const int oc = y + (i << 3);
    OH[(size_t)(c0 + oc) * R + r0 + x] = f2bf(t[x][oc]);
  }
}

// ---------------------------------------------------------------------------
// 2-level i8 GEMM (round-9 core: tile 128x256, 8 waves, BK=64, A 3-slot /
// B 2-slot LDS 112KB, 2-phase schedule, counted vmcnt(6), grouped raster).
// STORE: 0 = (+bias/relu) split-bf16 out; 2 = fp32 transposed ST[n][m] batched.
// ---------------------------------------------------------------------------
DEV i32x4 mfma_i8(i32x4 a, i32x4 b, i32x4 c) {
  return __builtin_amdgcn_mfma_i32_16x16x64_i8(a, b, c, 0, 0, 0);
}
DEV i32x4 rfi8(const signed char* base, int lstride, int L, int row, int fg) {
  return *(const i32x4*)&base[L * lstride + row * 64 + ((fg ^ ((row >> 1) & 3)) << 4)];
}

template <bool RELU, int STORE>
__launch_bounds__(512, 2)
__global__ void gemm_i8_k(unsigned char* wsb,
                          size_t a1o, size_t a2o, size_t b1o, size_t b2o,
                          size_t aso, size_t bso, const float* __restrict__ bias,
                          size_t o0, size_t o1, int M, int N, int K,
                          int gx, int gxy, int grp) {
  __shared__ alignas(16) signed char lds8[114688];

  unsigned char* ws = wsbase(wsb);
  const int tid = threadIdx.x;
  const int lane = tid & 63;
  const int wave = tid >> 6;
  const int wm = (wave >> 2) << 6;   // 0 / 64
  const int wn = (wave & 3) << 6;    // 0 / 64 / 128 / 192
  const int fr = lane & 15;
  const int fg = lane >> 4;

  // bijective XCD swizzle (nwg multiple of 8) + grouped raster
  const int nwg = gridDim.x;
  const int q8 = nwg >> 3;
  const int id = (blockIdx.x & 7) * q8 + (blockIdx.x >> 3);
  const int bz = id / gxy;
  const int rem = id - bz * gxy;
  int by, bx;
  raster2d(rem, gx, grp, by, bx);
  const int brow = by << 7;    // 128-row tiles
  const int bcol = bx << 8;    // 256-col tiles

  const size_t batchA = (size_t)bz * M * K;
  const size_t batchB = (STORE == 2) ? (size_t)bz * N * K : 0;
  const signed char* Xa1 = (const signed char*)(ws + a1o) + batchA;
  const signed char* Xa2 = (const signed char*)(ws + a2o) + batchA;
  const signed char* Wa1 = (const signed char*)(ws + b1o) + batchB;
  const signed char* Wa2 = (const signed char*)(ws + b2o) + batchB;
  const float* AS = (const float*)(ws + aso) + (size_t)bz * M;
  const float* BS = (const float*)(ws + bso) + ((STORE == 2) ? (size_t)bz * N : 0);

  // staging source offsets (granule-swizzled, granule = 16 i8)
  const int ar = tid >> 2, ac = tid & 3;
  const size_t aOff = (size_t)(brow + ar) * K + ((ac ^ ((ar >> 1) & 3)) << 4);
  size_t bOff[2];
#pragma unroll
  for (int h = 0; h < 2; ++h) {
    const int G = tid + h * 512;
    const int r = G >> 2, c = G & 3;
    bOff[h] = (size_t)(bcol + r) * K + ((c ^ ((r >> 1) & 3)) << 4);
  }

  auto stageA = [&](int slotBase, int tt) {   // 2 gl16
    const int ko = tt * 64;
    gl16b(Xa1 + aOff + ko, &lds8[slotBase + (tid << 4)]);
    gl16b(Xa2 + aOff + ko, &lds8[slotBase + 8192 + (tid << 4)]);
  };
  auto stageB = [&](int slotBase, int tt) {   // 4 gl16
    const int ko = tt * 64;
#pragma unroll
    for (int h = 0; h < 2; ++h) {
      gl16b(Wa1 + bOff[h] + ko, &lds8[slotBase + ((tid + h * 512) << 4)]);
      gl16b(Wa2 + bOff[h] + ko, &lds8[slotBase + 16384 + ((tid + h * 512) << 4)]);
    }
  };

  const int nt = K / 64;
  i32x4 I1[4][4] = {};
  i32x4 I2[4][4] = {};

  // prologue: A0,B0,A1,B1
  stageA(0, 0);
  stageB(49152, 0);
  if (nt > 1) { stageA(16384, 1); stageB(49152 + 32768, 1); }
  if (nt > 1) { asm volatile("s_waitcnt vmcnt(6)" ::: "memory"); }
  else        { asm volatile("s_waitcnt vmcnt(0)" ::: "memory"); }
  __builtin_amdgcn_s_barrier();

  for (int t = 0; t < nt; ++t) {
    const signed char* aS = &lds8[(t % 3) * 16384];
    const signed char* bS = &lds8[49152 + (t & 1) * 32768];
    const int sA2 = ((t + 2) % 3) * 16384;
    const int sB2 = 49152 + (t & 1) * 32768;
    const bool pf = (t + 2 < nt);
    i32x4 bf[4][2], af[2][2];

    // ---- phase A: stage A(t+2); read all B frags + A rows 0-1; MFMA half 0 ----
    if (pf) stageA(sA2, t + 2);
#pragma unroll
    for (int j = 0; j < 4; ++j) {
      bf[j][0] = rfi8(bS, 16384, 0, wn + j * 16 + fr, fg);
      bf[j][1] = rfi8(bS, 16384, 1, wn + j * 16 + fr, fg);
    }
#pragma unroll
    for (int i = 0; i < 2; ++i) {
      af[i][0] = rfi8(aS, 8192, 0, wm + i * 16 + fr, fg);
      af[i][1] = rfi8(aS, 8192, 1, wm + i * 16 + fr, fg);
    }
    __builtin_amdgcn_s_setprio(1);
#pragma unroll
    for (int i = 0; i < 2; ++i)
#pragma unroll
      for (int j = 0; j < 4; ++j) {
        I1[i][j] = mfma_i8(af[i][0], bf[j][0], I1[i][j]);
        I2[i][j] = mfma_i8(af[i][0], bf[j][1], I2[i][j]);
        I2[i][j] = mfma_i8(af[i][1], bf[j][0], I2[i][j]);
      }
    __builtin_amdgcn_s_setprio(0);
    __builtin_amdgcn_s_barrier();

    // ---- phase B: stage B(t+2); read A rows 2-3; MFMA half 1; counted vmcnt ----
    asm volatile("" ::: "memory");
    if (pf) stageB(sB2, t + 2);
#pragma unroll
    for (int i = 0; i < 2; ++i) {
      af[i][0] = rfi8(aS, 8192, 0, wm + (2 + i) * 16 + fr, fg);
      af[i][1] = rfi8(aS, 8192, 1, wm + (2 + i) * 16 + fr, fg);
    }
    __builtin_amdgcn_s_setprio(1);
#pragma unroll
    for (int i = 0; i < 2; ++i)
#pragma unroll
      for (int j = 0; j < 4; ++j) {
        I1[2 + i][j] = mfma_i8(af[i][0], bf[j][0], I1[2 + i][j]);
        I2[2 + i][j] = mfma_i8(af[i][0], bf[j][1], I2[2 + i][j]);
        I2[2 + i][j] = mfma_i8(af[i][1], bf[j][0], I2[2 + i][j]);
      }
    __builtin_amdgcn_s_setprio(0);
    if (pf) { asm volatile("s_waitcnt vmcnt(6)" ::: "memory"); }
    else    { asm volatile("s_waitcnt vmcnt(0)" ::: "memory"); }
    __builtin_amdgcn_s_barrier();
  }

  const int fq4 = fg << 2;
  if constexpr (STORE == 0) {
    // ---- dequant + bias (+relu) -> split-bf16 via LDS bounce, NT stores ----
    short* ldsS = (short*)lds8;
    short* Oh = (short*)(ws + o0);
    short* Ol = (short*)(ws + o1);
#pragma unroll
    for (int rd = 0; rd < 2; ++rd) {
      __builtin_amdgcn_s_barrier();
#pragma unroll
      for (int i = 0; i < 4; ++i) {
        const int rl = wm + i * 16 + fq4;
        const f32x4 sa4 = *(const f32x4*)&AS[brow + rl];
#pragma unroll
        for (int j = 0; j < 4; ++j) {
          const int cl = wn + j * 16 + fr;
          const float sb = BS[bcol + cl];
          const float bv = bias ? bias[bcol + cl] : 0.0f;
#pragma unroll
          for (int e = 0; e < 4; ++e) {
            float u = ((float)I1[i][j][e] + (float)I2[i][j][e] * (1.0f / 256.0f)) *
                          (sa4[e] * sb) + bv;
            if (RELU) u = fmaxf(u, 0.0f);
            short v;
            if (rd == 0) {
              v = f2bf(u);
            } else {
              const short hb = f2bf(u);
              v = f2bf(u - bf2f(hb));
            }
            ldsS[(rl + e) * 264 + cl] = v;
          }
        }
      }
      __builtin_amdgcn_s_barrier();
      short* gout = (rd == 0) ? Oh : Ol;
#pragma unroll
      for (int gi = 0; gi < 8; ++gi) {
        const int g = gi * 512 + tid;
        const int row = g >> 5, cg = g & 31;
        const short8 v = *(const short8*)&ldsS[row * 264 + cg * 8];
        nts(v, (short8*)&gout[(size_t)(brow + row) * N + bcol + cg * 8]);
      }
    }
  } else {
    // ---- dequant -> fp32 TRANSPOSED ST[n][m] via LDS bounce (batched) ----
    float* Of = (float*)(ws + o0) + (size_t)bz * M * N;
    float* ldsf = (float*)lds8;
#pragma unroll
    for (int h2 = 0; h2 < 2; ++h2) {
      __builtin_amdgcn_s_barrier();
      if ((wn >> 7) == h2) {
#pragma unroll
        for (int i = 0; i < 4; ++i) {
          const int rl = wm + i * 16 + fq4;
          const f32x4 sa4 = *(const f32x4*)&AS[brow + rl];
#pragma unroll
          for (int j = 0; j < 4; ++j) {
            const int cp = (wn & 127) + j * 16 + fr;
            const float sb = BS[bcol + wn + j * 16 + fr];
            f32x4 u;
#pragma unroll
            for (int e = 0; e < 4; ++e)
              u[e] = ((float)I1[i][j][e] + (float)I2[i][j][e] * (1.0f / 256.0f)) *
                     (sa4[e] * sb);
            *(f32x4*)&ldsf[cp * 132 + rl] = u;
          }
        }
      }
      __builtin_amdgcn_s_barrier();
#pragma unroll
      for (int gi = 0; gi < 8; ++gi) {
        const int g = gi * 512 + tid;
        const int tr = g >> 5, tc4 = (g & 31) << 2;
        const f32x4 v = *(const f32x4*)&ldsf[tr * 132 + tc4];
        nts(v, (f32x4*)&Of[(size_t)(bcol + h2 * 128 + tr) * M + brow + tc4]);
      }
    }
  }
}

// ---------------------------------------------------------------------------
// 256x256-tile 8-wave pipelined bf16 GEMM + grouped raster (round-9 core).
// STORE: 1 bf16 out, 3 fp32 optr bounce.
// ---------------------------------------------------------------------------
constexpr int CH = 8192;        // shorts per 16KB chunk

DEV short8 read_frag1(const short* base, int row, int s, int fg) {
  return *(const short8*)&base[row * 64 + ((((s << 2) | fg) ^ (row & 7)) << 3)];
}

DEV f32x4 mfma16(short8 a, short8 b, f32x4 c) {
  return __builtin_amdgcn_mfma_f32_16x16x32_bf16(a, b, c, 0, 0, 0);
}

template <bool RELU, int STORE>
__launch_bounds__(512, 2)
__global__ void gemm8_k(unsigned char* wsb,
                        size_t aoff0, size_t boff0,
                        const float* __restrict__ bias,
                        size_t ooff0, float* __restrict__ optr,
                        int M, int N, int K, int gx, int gxy, int grp) {
  __shared__ alignas(16) short lds[10 * CH];

  unsigned char* ws = wsbase(wsb);
  const int tid = threadIdx.x;
  const int lane = tid & 63;
  const int wave = tid >> 6;
  const int wm = (wave >> 2) << 7;   // 0 / 128
  const int wn = (wave & 3) << 6;    // 0 / 64 / 128 / 192

  const int nwg = gridDim.x;
  const int q8 = nwg >> 3;
  const int id = (blockIdx.x & 7) * q8 + (blockIdx.x >> 3);
  const int bz = id / gxy;
  const int rem = id - bz * gxy;
  int by, bx;
  raster2d(rem, gx, grp, by, bx);
  const int brow = by << 8;
  const int bcol = bx << 8;

  const short* A0 = (const short*)(ws + aoff0) + (size_t)bz * M * K;
  const short* B0g = (const short*)(ws + boff0) + (size_t)bz * N * K;

  size_t aSrc[2][2], bSrc[2][2];
#pragma unroll
  for (int h = 0; h < 2; ++h) {
    const int G = tid + h * 512;
    const int r = G >> 3, c = G & 7;
#pragma unroll
    for (int qq = 0; qq < 2; ++qq) {
      aSrc[qq][h] = (size_t)(brow + qq * 128 + r) * K + (size_t)((c ^ (r & 7)) << 3);
      bSrc[qq][h] = (size_t)(bcol + qq * 128 + r) * K + (size_t)((c ^ (r & 7)) << 3);
    }
  }
  const int ldst0 = tid << 3;

  auto issueA = [&](int slot, int qq, int tt) {
    short* dst = &lds[slot + qq * CH];
    const size_t ka = (size_t)tt * 64;
    gl16(A0 + aSrc[qq][0] + ka, dst + ldst0);
    gl16(A0 + aSrc[qq][1] + ka, dst + ldst0 + CH / 2);
  };
  auto issueB = [&](int slot, int qq, int tt) {
    short* dst = &lds[slot + qq * CH];
    const size_t ka = (size_t)tt * 64;
    gl16(B0g + bSrc[qq][0] + ka, dst + ldst0);
    gl16(B0g + bSrc[qq][1] + ka, dst + ldst0 + CH / 2);
  };

  const int nt = K / 64;
  const int fr = lane & 15;
  const int fg = lane >> 4;

  f32x4 acc[8][4] = {};

  issueA(0, 0, 0); issueA(0, 1, 0);
  issueB(6 * CH, 0, 0); issueB(6 * CH, 1, 0);
  if (nt > 1) {
    issueA(2 * CH, 0, 1); issueA(2 * CH, 1, 1);
    issueB(8 * CH, 0, 1); issueB(8 * CH, 1, 1);
    asm volatile("s_waitcnt vmcnt(8)" ::: "memory");
  } else {
    asm volatile("s_waitcnt vmcnt(0)" ::: "memory");
  }
  __builtin_amdgcn_s_barrier();

  for (int t = 0; t < nt; ++t) {
    const short* aBase = &lds[(t % 3) * (2 * CH)];
    const short* bBase = &lds[6 * CH + (t & 1) * (2 * CH)];
    const int sA2 = ((t + 2) % 3) * (2 * CH);
    const int sB  = 6 * CH + (t & 1) * (2 * CH);
    const bool pf = (t + 2 < nt);
    short8 bfr[4][2], av[4][2];

    if (pf) { issueA(sA2, 0, t + 2); issueA(sA2, 1, t + 2); }
#pragma unroll
    for (int j = 0; j < 4; ++j) {
      bfr[j][0] = read_frag1(bBase, wn + j * 16 + fr, 0, fg);
      bfr[j][1] = read_frag1(bBase, wn + j * 16 + fr, 1, fg);
    }
#pragma unroll
    for (int i = 0; i < 4; ++i) {
      av[i][0] = read_frag1(aBase, wm + i * 16 + fr, 0, fg);
      av[i][1] = read_frag1(aBase, wm + i * 16 + fr, 1, fg);
    }
    __builtin_amdgcn_s_setprio(1);
#pragma unroll
    for (int i = 0; i < 4; ++i)
#pragma unroll
      for (int j = 0; j < 4; ++j) {
        acc[i][j] = mfma16(av[i][0], bfr[j][0], acc[i][j]);
        acc[i][j] = mfma16(av[i][1], bfr[j][1], acc[i][j]);
      }
    __builtin_amdgcn_s_setprio(0);
    __builtin_amdgcn_s_barrier();

    asm volatile("" ::: "memory");
    if (pf) { issueB(sB, 0, t + 2); issueB(sB, 1, t + 2); }
#pragma unroll
    for (int i = 0; i < 4; ++i) {
      av[i][0] = read_frag1(aBase, wm + 64 + i * 16 + fr, 0, fg);
      av[i][1] = read_frag1(aBase, wm + 64 + i * 16 + fr, 1, fg);
    }
    __builtin_amdgcn_s_setprio(1);
#pragma unroll
    for (int i = 0; i < 4; ++i)
#pragma unroll
      for (int j = 0; j < 4; ++j) {
        acc[4 + i][j] = mfma16(av[i][0], bfr[j][0], acc[4 + i][j]);
        acc[4 + i][j] = mfma16(av[i][1], bfr[j][1], acc[4 + i][j]);
      }
    __builtin_amdgcn_s_setprio(0);
    if (pf) {
      asm volatile("s_waitcnt vmcnt(8)" ::: "memory");
    } else {
      asm volatile("s_waitcnt vmcnt(0)" ::: "memory");
    }
    __builtin_amdgcn_s_barrier();
  }

  // ---- epilogue ----
  const int fq4 = (lane >> 4) << 2;
  if constexpr (STORE == 1) {
    short* Oh = (short*)(ws + ooff0);
    __builtin_amdgcn_s_barrier();
#pragma unroll
    for (int i = 0; i < 8; ++i) {
      const int rl = wm + i * 16 + fq4;
#pragma unroll
      for (int j = 0; j < 4; ++j) {
        const int cl = wn + j * 16 + fr;
        const float bv = bias ? bias[bcol + cl] : 0.0f;
#pragma unroll
        for (int e = 0; e < 4; ++e) {
          float u = acc[i][j][e] + bv;
          if (RELU) u = fmaxf(u, 0.0f);
          lds[(rl + e) * 264 + cl] = f2bf(u);
        }
      }
    }
    __builtin_amdgcn_s_barrier();
#pragma unroll
    for (int gi = 0; gi < 16; ++gi) {
      const int g = gi * 512 + tid;
      const int row = g >> 5, cg = g & 31;
      const short8 v = *(const short8*)&lds[row * 264 + cg * 8];
      nts(v, (short8*)&Oh[(size_t)(brow + row) * N + bcol + cg * 8]);
    }
  } else {
    float* Op = optr + (size_t)bz * M * N;
    float* ldsf = (float*)lds;
#pragma unroll
    for (int h = 0; h < 2; ++h) {
      __builtin_amdgcn_s_barrier();
      if ((wm & 128) == (h << 7)) {
#pragma unroll
        for (int i = 0; i < 8; ++i) {
          const int rp = (wm & 127) + i * 16 + fq4;
#pragma unroll
          for (int j = 0; j < 4; ++j) {
            const int cl = wn + j * 16 + fr;
#pragma unroll
            for (int e = 0; e < 4; ++e)
              ldsf[(rp + e) * 258 + cl] = acc[i][j][e];
          }
        }
      }
      __builtin_amdgcn_s_barrier();
#pragma unroll
      for (int gi = 0; gi < 16; ++gi) {
        const int g = gi * 512 + tid;
        const int tr = g >> 6, tc4 = (g & 63) << 2;
        const f32x4 v = *(const f32x4*)&ldsf[tr * 258 + tc4];
        nts(v, (f32x4*)&Op[(size_t)(brow + h * 128 + tr) * N + bcol + tc4]);
      }
    }
  }
}

// ---------------------------------------------------------------------------
// row softmax over ST rows (axis-1 softmax of scores), output bf16 probs^T
// ---------------------------------------------------------------------------
__launch_bounds__(256)
__global__ void softmax_rows_k(unsigned char* wsb, size_t st, size_t pt) {
  constexpr int S = 2048;
  unsigned char* ws = wsbase(wsb);
  const f32x4* row = (const f32x4*)((const float*)(ws + st) + (size_t)blockIdx.x * S);
  short4v* out = (short4v*)((short*)(ws + pt) + (size_t)blockIdx.x * S);
  const int tid = threadIdx.x, lane = tid & 63, wv = tid >> 6;
  const f32x4 a = ntl(&row[tid]);
  const f32x4 b = ntl(&row[tid + 256]);
  float m = fmaxf(fmaxf(fmaxf(a[0], a[1]), fmaxf(a[2], a[3])),
                  fmaxf(fmaxf(b[0], b[1]), fmaxf(b[2], b[3])));
#pragma unroll
  for (int o = 32; o; o >>= 1) m = fmaxf(m, __shfl_xor(m, o));
  __shared__ float rb[8];
  if (lane == 0) rb[wv] = m;
  __syncthreads();
  m = fmaxf(fmaxf(rb[0], rb[1]), fmaxf(rb[2], rb[3]));
  float e[8];
  float s = 0.0f;
#pragma unroll
  for (int q = 0; q < 4; ++q) { e[q] = expf(a[q] - m); s += e[q]; }
#pragma unroll
  for (int q = 0; q < 4; ++q) { e[4 + q] = expf(b[q] - m); s += e[4 + q]; }
#pragma unroll
  for (int o = 32; o; o >>= 1) s += __shfl_xor(s, o);
  if (lane == 0) rb[4 + wv] = s;
  __syncthreads();
  s = rb[4] + rb[5] + rb[6] + rb[7];
  const float inv = 1.0f / s;
  short4v o1, o2;
#pragma unroll
  for (int q = 0; q < 4; ++q) { o1[q] = f2bf(e[q] * inv); o2[q] = f2bf(e[4 + q] * inv); }
  nts(o1, &out[tid]);
  nts(o2, &out[tid + 256]);
}

// ---------------------------------------------------------------------------
extern "C" void kernel_launch(void* const* d_in, const int* in_sizes, int n_in,
                              void* d_out, int out_size, void* d_ws, size_t ws_size,
                              hipStream_t stream) {
  const float* x   = (const float*)d_in[0];
  const float* qw1 = (const float*)d_in[1];
  const float* qb1 = (const float*)d_in[2];
  const float* qw2 = (const float*)d_in[3];
  const float* qb2 = (const float*)d_in[4];
  const float* kw1 = (const float*)d_in[5];
  const float* kb1 = (const float*)d_in[6];
  const float* kw2 = (const float*)d_in[7];
  const float* kb2 = (const float*)d_in[8];
  const float* vw1 = (const float*)d_in[9];
  const float* vb1 = (const float*)d_in[10];
  const float* vw2 = (const float*)d_in[11];
  const float* vb2 = (const float*)d_in[12];
  float* out = (float*)d_out;
  unsigned char* wsb = (ws_size >= WS_TOTAL) ? (unsigned char*)d_ws : nullptr;
  unsigned char* wsr;
  if (wsb) wsr = wsb;
  else { hipError_t e = hipGetSymbolAddress((void**)&wsr, HIP_SYMBOL(g_ws)); (void)e; }

  const int M = BB * SS;  // 8192
  dim3 blk(512);
  dim3 tb(32, 8);

  // x -> i8 2-level (Q/K MLP1) and bf16 hi (V MLP1)
  quant_x_k<<<8192, 256, 0, stream>>>(x, wsb, OFF_XA1, OFF_XA2, OFF_XS);
  cast_hi_k<<<4096, 256, 0, stream>>>(x, wsb, OFF_XH, NX / 4);

  // ================= Q path (all i8) =================
  hipMemsetAsync(wsr + OFF_CM, 0, 32768, stream);
  colmax_k<<<dim3(HHID / 256, DD / 128), 256, 0, stream>>>(qw1, wsb, OFF_CM, DD, HHID);
  scalefix_k<<<32, 256, 0, stream>>>(wsb, OFF_CM, HHID);
  transpose_quant_k<<<dim3(HHID / 32, DD / 32), tb, 0, stream>>>(qw1, wsb, OFF_WA1, OFF_WA2, OFF_CM, DD, HHID);
  gemm_i8_k<true, 0><<<2048, blk, 0, stream>>>(wsb, OFF_XA1, OFF_XA2, OFF_WA1, OFF_WA2,
                                               OFF_XS, OFF_CM, qb1, OFF_HH, OFF_HL,
                                               M, HHID, DD, 32, 2048, 8);
  rowquant_k<<<8192, 1024, 0, stream>>>(wsb, OFF_HH, OFF_HL, OFF_HA1, OFF_HA2, OFF_HS, HHID);
  hipMemsetAsync(wsr + OFF_CM, 0, 32768, stream);
  colmax_k<<<dim3(DD / 256, HHID / 128), 256, 0, stream>>>(qw2, wsb, OFF_CM, HHID, DD);
  scalefix_k<<<8, 256, 0, stream>>>(wsb, OFF_CM, DD);
  transpose_quant_k<<<dim3(DD / 32, HHID / 32), tb, 0, stream>>>(qw2, wsb, OFF_WA1, OFF_WA2, OFF_CM, HHID, DD);
  gemm_i8_k<false, 0><<<512, blk, 0, stream>>>(wsb, OFF_HA1, OFF_HA2, OFF_WA1, OFF_WA2,
                                               OFF_HS, OFF_CM, qb2, OFF_QKH, OFF_QKL,
                                               M, DD, HHID, 8, 512, 8);
  rowquant_k<<<8192, 256, 0, stream>>>(wsb, OFF_QKH, OFF_QKL, OFF_QA1, OFF_QA2, OFF_QS, DD);

  // ================= K path (all i8) =================
  hipMemsetAsync(wsr + OFF_CM, 0, 32768, stream);
  colmax_k<<<dim3(HHID / 256, DD / 128), 256, 0, stream>>>(kw1, wsb, OFF_CM, DD, HHID);
  scalefix_k<<<32, 256, 0, stream>>>(wsb, OFF_CM, HHID);
  transpose_quant_k<<<dim3(HHID / 32, DD / 32), tb, 0, stream>>>(kw1, wsb, OFF_WA1, OFF_WA2, OFF_CM, DD, HHID);
  gemm_i8_k<true, 0><<<2048, blk, 0, stream>>>(wsb, OFF_XA1, OFF_XA2, OFF_WA1, OFF_WA2,
                                               OFF_XS, OFF_CM, kb1, OFF_HH, OFF_HL,
                                               M, HHID, DD, 32, 2048, 8);
  rowquant_k<<<8192, 1024, 0, stream>>>(wsb, OFF_HH, OFF_HL, OFF_HA1, OFF_HA2, OFF_HS, HHID);
  hipMemsetAsync(wsr + OFF_CM, 0, 32768, stream);
  colmax_k<<<dim3(DD / 256, HHID / 128), 256, 0, stream>>>(kw2, wsb, OFF_CM, HHID, DD);
  scalefix_k<<<8, 256, 0, stream>>>(wsb, OFF_CM, DD);
  transpose_quant_k<<<dim3(DD / 32, HHID / 32), tb, 0, stream>>>(kw2, wsb, OFF_WA1, OFF_WA2, OFF_CM, HHID, DD);
  gemm_i8_k<false, 0><<<512, blk, 0, stream>>>(wsb, OFF_HA1, OFF_HA2, OFF_WA1, OFF_WA2,
                                               OFF_HS, OFF_CM, kb2, OFF_QKH, OFF_QKL,
                                               M, DD, HHID, 8, 512, 8);
  rowquant_k<<<8192, 256, 0, stream>>>(wsb, OFF_QKH, OFF_QKL, OFF_KA1, OFF_KA2, OFF_KS, DD);

  // ================= V path (plain bf16) =================
  transpose_cast_k<<<dim3(HHID / 32, DD / 32), tb, 0, stream>>>(vw1, wsb, OFF_WHV, DD, HHID);
  gemm8_k<true, 1><<<1024, blk, 0, stream>>>(
      wsb, OFF_XH, OFF_WHV, vb1, OFF_HH, nullptr, M, HHID, DD, 32, 1024, 4);
  transpose_cast_k<<<dim3(DD / 32, HHID / 32), tb, 0, stream>>>(vw2, wsb, OFF_WHV, HHID, DD);
  gemm8_k<false, 1><<<256, blk, 0, stream>>>(
      wsb, OFF_HH, OFF_WHV, vb2, OFF_V, nullptr, M, DD, HHID, 8, 256, 4);

  // ---- scores^T (i8, batched): ST[t][s] per batch ----
  gemm_i8_k<false, 2><<<512, blk, 0, stream>>>(wsb, OFF_QA1, OFF_QA2, OFF_KA1, OFF_KA2,
                                               OFF_QS, OFF_KS, nullptr, OFF_ST, 0,
                                               SS, SS, DD, 8, 128, 8);

  // ---- softmax over axis 1 == row softmax of ST; writes bf16 probs^T ----
  softmax_rows_k<<<BB * SS, 256, 0, stream>>>(wsb, OFF_ST, OFF_PT);

  // ---- out = V @ probs (B^T = probs^T), fp32 to d_out ----
  gemm8_k<false, 3><<<256, blk, 0, stream>>>(
      wsb, OFF_V, OFF_PT, nullptr, 0, out, SS, SS, DD, 8, 64, 4);
}